// Round 1
// baseline (1783.880 us; speedup 1.0000x reference)
//
#include <hip/hip_runtime.h>
#include <cstdint>
#include <cstddef>

#define F       256
#define NCLASS  47
#define CSR_W   64

#define NSRC0 1081344
#define NDST0 67584
#define NE0   1013760
#define NSRC1 67584
#define NDST1 6144
#define NE1   61440
#define NSRC2 6144
#define NDST2 1024
#define NE2   5120

// ---- workspace layout (bytes) ----
#define O_CNTSRC0 ((size_t)0)
#define O_CURDST0 (O_CNTSRC0 + (size_t)NSRC0 * 4)
#define O_CNTSRC1 (O_CURDST0 + (size_t)NDST0 * 4)
#define O_CURDST1 (O_CNTSRC1 + (size_t)NSRC1 * 4)
#define O_CNTSRC2 (O_CURDST1 + (size_t)NDST1 * 4)
#define O_CURDST2 (O_CNTSRC2 + (size_t)NSRC2 * 4)
#define ZBYTES    (O_CURDST2 + (size_t)NDST2 * 4)           // ~4.9 MB zeroed each call
#define O_CSR0    ZBYTES
#define O_CSR1    (O_CSR0 + (size_t)NDST0 * CSR_W * 4)
#define O_CSR2    (O_CSR1 + (size_t)NDST1 * CSR_W * 4)
#define O_AGG0    (O_CSR2 + (size_t)NDST2 * CSR_W * 4)
#define O_AGG1    (O_AGG0 + (size_t)NDST0 * F * 4)
#define O_AGG2    (O_AGG1 + (size_t)NDST1 * F * 4)
// total = O_AGG2 + 1024*256*4 = 100,601,856 bytes (~96 MB)

// ---------------------------------------------------------------------------
// Edge-parallel CSR build: counts src-degree, scatters src ids into stride-64
// CSR rows keyed by dst. cursor array doubles as deg_in after this kernel.
// ---------------------------------------------------------------------------
__global__ __launch_bounds__(256) void build_csr(
    const int* __restrict__ src, const int* __restrict__ dst, int nE,
    unsigned* __restrict__ cnt_src, unsigned* __restrict__ cur_dst,
    int* __restrict__ csr) {
  int e = blockIdx.x * blockDim.x + threadIdx.x;
  if (e >= nE) return;
  int s = src[e];
  int d = dst[e];
  atomicAdd(&cnt_src[s], 1u);
  unsigned pos = atomicAdd(&cur_dst[d], 1u);
  if (pos < CSR_W) csr[(size_t)d * CSR_W + pos] = s;
}

// ---------------------------------------------------------------------------
// Wave-per-dst aggregation: acc = deg_in^-1/2 * sum_e deg_out^-1/2 * feat[src_e]
// Edge ids + src scales prefetched into lanes, broadcast with __shfl.
// Each edge costs one coalesced 1KB row read.
// ---------------------------------------------------------------------------
__global__ __launch_bounds__(256) void gather_kernel(
    const float* __restrict__ feat, const int* __restrict__ csr,
    const unsigned* __restrict__ cnt_src, const unsigned* __restrict__ cur_dst,
    float* __restrict__ out, int nDst) {
  int gid  = blockIdx.x * blockDim.x + threadIdx.x;
  int d    = gid >> 6;
  int lane = threadIdx.x & 63;
  if (d >= nDst) return;

  unsigned deg_full = cur_dst[d];
  unsigned deg = deg_full < CSR_W ? deg_full : CSR_W;
  float scale_in = rsqrtf((float)(deg_full > 0u ? deg_full : 1u));

  int   s_l  = 0;
  float so_l = 0.f;
  if (lane < (int)deg) {
    s_l = csr[(size_t)d * CSR_W + lane];
    unsigned c = cnt_src[s_l];
    so_l = rsqrtf((float)(c > 0u ? c : 1u));
  }

  float4 acc = make_float4(0.f, 0.f, 0.f, 0.f);
  for (int j = 0; j < (int)deg; ++j) {
    int   s  = __shfl(s_l, j);
    float so = __shfl(so_l, j);
    float4 v = *(const float4*)(feat + (size_t)s * F + lane * 4);
    acc.x = fmaf(so, v.x, acc.x);
    acc.y = fmaf(so, v.y, acc.y);
    acc.z = fmaf(so, v.z, acc.z);
    acc.w = fmaf(so, v.w, acc.w);
  }
  acc.x *= scale_in; acc.y *= scale_in; acc.z *= scale_in; acc.w *= scale_in;
  *(float4*)(out + (size_t)d * F + lane * 4) = acc;
}

// ---------------------------------------------------------------------------
// In-place row transform: A[M,256] = act(A @ W[256,256] + b).
// Block owns 32 full rows (full col width => in-place is race-free).
// BK=32; A staged transposed in LDS (pad 36 keeps float4 alignment, <=4-way
// store conflict); thread computes 8 rows x 4 cols = 32 FMA per 3 b128 reads.
// ---------------------------------------------------------------------------
#define TBM 32
#define TBK 32
#define APAD 36

__global__ __launch_bounds__(256) void transform_kernel(
    float* __restrict__ A, const float* __restrict__ W,
    const float* __restrict__ bias, int do_relu) {
  __shared__ float As[TBK * APAD];   // [kk][row]
  __shared__ float Ws[TBK * F];      // [kk][n]
  const int t    = threadIdx.x;
  const int row0 = blockIdx.x * TBM;
  const int c4   = (t & 63) * 4;     // 4 output cols (lane-contiguous b128 on Ws)
  const int r8   = (t >> 6) * 8;     // 8 output rows (broadcast b128 on As)
  const int row_a = t >> 3;          // A staging: row
  const int kq    = (t & 7) * 4;     // A staging: 4 consecutive k

  float acc[8][4] = {};

  for (int k0 = 0; k0 < F; k0 += TBK) {
    float4 av = *(const float4*)(A + (size_t)(row0 + row_a) * F + k0 + kq);
    float4 wv[8];
#pragma unroll
    for (int i = 0; i < 8; ++i) {
      int idx = i * 256 + t;         // float4 index into 32x256 tile
      int kk  = idx >> 6;
      int n4  = (idx & 63) * 4;
      wv[i] = *(const float4*)(W + (size_t)(k0 + kk) * F + n4);
    }
    if (k0) __syncthreads();
    As[(kq + 0) * APAD + row_a] = av.x;
    As[(kq + 1) * APAD + row_a] = av.y;
    As[(kq + 2) * APAD + row_a] = av.z;
    As[(kq + 3) * APAD + row_a] = av.w;
#pragma unroll
    for (int i = 0; i < 8; ++i) {
      int idx = i * 256 + t;
      int kk  = idx >> 6;
      int n4  = (idx & 63) * 4;
      *(float4*)(Ws + kk * F + n4) = wv[i];
    }
    __syncthreads();
#pragma unroll
    for (int kk = 0; kk < TBK; ++kk) {
      float4 w  = *(const float4*)(Ws + kk * F + c4);
      float4 a0 = *(const float4*)(As + kk * APAD + r8);
      float4 a1 = *(const float4*)(As + kk * APAD + r8 + 4);
      float ar[8] = {a0.x, a0.y, a0.z, a0.w, a1.x, a1.y, a1.z, a1.w};
      float wr[4] = {w.x, w.y, w.z, w.w};
#pragma unroll
      for (int r = 0; r < 8; ++r)
#pragma unroll
        for (int c = 0; c < 4; ++c)
          acc[r][c] = fmaf(ar[r], wr[c], acc[r][c]);
    }
  }

  float4 bv = *(const float4*)(bias + c4);
#pragma unroll
  for (int r = 0; r < 8; ++r) {
    float4 o;
    o.x = acc[r][0] + bv.x;
    o.y = acc[r][1] + bv.y;
    o.z = acc[r][2] + bv.z;
    o.w = acc[r][3] + bv.w;
    if (do_relu) {
      o.x = fmaxf(o.x, 0.f); o.y = fmaxf(o.y, 0.f);
      o.z = fmaxf(o.z, 0.f); o.w = fmaxf(o.w, 0.f);
    }
    *(float4*)(A + (size_t)(row0 + r8 + r) * F + c4) = o;
  }
}

// ---------------------------------------------------------------------------
// Final 256->47 layer (25 MFLOP): thread per (row, col<47), no activation.
// ---------------------------------------------------------------------------
__global__ __launch_bounds__(256) void final_kernel(
    const float* __restrict__ A, const float* __restrict__ W2,
    const float* __restrict__ b2, float* __restrict__ out) {
  int idx = blockIdx.x * blockDim.x + threadIdx.x;
  int row = idx >> 6;
  int col = idx & 63;
  if (row >= NDST2 || col >= NCLASS) return;
  const float* a = A + (size_t)row * F;
  float acc = 0.f;
#pragma unroll 8
  for (int k = 0; k < F; ++k) acc = fmaf(a[k], W2[k * NCLASS + col], acc);
  out[row * NCLASS + col] = acc + b2[col];
}

extern "C" void kernel_launch(void* const* d_in, const int* in_sizes, int n_in,
                              void* d_out, int out_size, void* d_ws, size_t ws_size,
                              hipStream_t stream) {
  const float* x    = (const float*)d_in[0];
  const int*   src0 = (const int*)d_in[1];
  const int*   dst0 = (const int*)d_in[2];
  const int*   src1 = (const int*)d_in[3];
  const int*   dst1 = (const int*)d_in[4];
  const int*   src2 = (const int*)d_in[5];
  const int*   dst2 = (const int*)d_in[6];
  const float* W0   = (const float*)d_in[7];
  const float* b0   = (const float*)d_in[8];
  const float* W1   = (const float*)d_in[9];
  const float* b1   = (const float*)d_in[10];
  const float* W2   = (const float*)d_in[11];
  const float* b2   = (const float*)d_in[12];
  float* out = (float*)d_out;
  char*  ws  = (char*)d_ws;

  unsigned* cnt_src0 = (unsigned*)(ws + O_CNTSRC0);
  unsigned* cur_dst0 = (unsigned*)(ws + O_CURDST0);
  unsigned* cnt_src1 = (unsigned*)(ws + O_CNTSRC1);
  unsigned* cur_dst1 = (unsigned*)(ws + O_CURDST1);
  unsigned* cnt_src2 = (unsigned*)(ws + O_CNTSRC2);
  unsigned* cur_dst2 = (unsigned*)(ws + O_CURDST2);
  int*   csr0 = (int*)(ws + O_CSR0);
  int*   csr1 = (int*)(ws + O_CSR1);
  int*   csr2 = (int*)(ws + O_CSR2);
  float* agg0 = (float*)(ws + O_AGG0);
  float* agg1 = (float*)(ws + O_AGG1);
  float* agg2 = (float*)(ws + O_AGG2);

  // ws is re-poisoned to 0xAA before every timed launch: re-zero the count zone.
  hipMemsetAsync(ws, 0, ZBYTES, stream);

  build_csr<<<NE0 / 256, 256, 0, stream>>>(src0, dst0, NE0, cnt_src0, cur_dst0, csr0);
  build_csr<<<NE1 / 256, 256, 0, stream>>>(src1, dst1, NE1, cnt_src1, cur_dst1, csr1);
  build_csr<<<NE2 / 256, 256, 0, stream>>>(src2, dst2, NE2, cnt_src2, cur_dst2, csr2);

  // layer 0: aggregate x -> agg0, transform in-place (+ReLU)
  gather_kernel<<<NDST0 / 4, 256, 0, stream>>>(x, csr0, cnt_src0, cur_dst0, agg0, NDST0);
  transform_kernel<<<NDST0 / TBM, 256, 0, stream>>>(agg0, W0, b0, 1);

  // layer 1
  gather_kernel<<<NDST1 / 4, 256, 0, stream>>>(agg0, csr1, cnt_src1, cur_dst1, agg1, NDST1);
  transform_kernel<<<NDST1 / TBM, 256, 0, stream>>>(agg1, W1, b1, 1);

  // layer 2: aggregate then 256->47 projection straight into d_out
  gather_kernel<<<NDST2 / 4, 256, 0, stream>>>(agg1, csr2, cnt_src2, cur_dst2, agg2, NDST2);
  final_kernel<<<(NDST2 * 64) / 256, 256, 0, stream>>>(agg2, W2, b2, out);
}